// Round 6
// baseline (345.225 us; speedup 1.0000x reference)
//
#include <hip/hip_runtime.h>
#include <hip/hip_bf16.h>

// Problem: B=8, T=2048, D_IN=D_EMB=D_OUT=1024
#define B_DIM 8
#define T_DIM 2048
#define E_DIM 1024

typedef __attribute__((ext_vector_type(8))) short short8;
typedef __attribute__((ext_vector_type(4))) float f32x4;

__device__ __forceinline__ unsigned short f2bf(float f) {
  union { float f; unsigned u; } v; v.f = f;
  unsigned r = v.u + 0x7fffu + ((v.u >> 16) & 1u);
  return (unsigned short)(r >> 16);
}
__device__ __forceinline__ float bf2f(unsigned short u) {
  union { unsigned u; float f; } v; v.u = ((unsigned)u) << 16;
  return v.f;
}

__device__ __forceinline__ void async16(const void* g, void* l) {
  __builtin_amdgcn_global_load_lds(
      (const __attribute__((address_space(1))) unsigned int*)g,
      (__attribute__((address_space(3))) unsigned int*)l, 16, 0, 0);
}

__device__ __forceinline__ void storeC(float* p, float v) { *p = v; }
__device__ __forceinline__ void storeC(unsigned short* p, float v) { *p = f2bf(v); }

// ---------------- fp32 -> bf16 conversion (vectorized) ----------------
__global__ __launch_bounds__(256) void cvt_bf16(const float4* __restrict__ in,
                                                ushort4* __restrict__ out) {
  size_t i = (size_t)blockIdx.x * 256 + threadIdx.x;
  float4 v = in[i];
  ushort4 o;
  o.x = f2bf(v.x); o.y = f2bf(v.y); o.z = f2bf(v.z); o.w = f2bf(v.w);
  out[i] = o;
}

// ============ 256x256 8-phase bf16 GEMM: C[M,N] = A[M,K]*B[N,K]^T (+epilogue) ========
// 512 threads = 8 waves (2M x 4N), per-wave 128x64 output, BK=64, 128KB LDS.
// Chunk swizzle q' = q ^ (row&7) on BOTH stage-source and ds_read (rule #21).
// m201-verbatim phase discipline: {reads ; stage ; [lgkmcnt(8) if 12 reads] ;
//   s_barrier ; asm lgkmcnt(0)+memory ; sched_barrier(0) ; setprio(1) ; 16 MFMA ;
//   setprio(0) ; [p3: counted vmcnt] ; s_barrier}.  The memory-clobber lgkmcnt(0)
// pins the ds_reads in the issue window (compiler cannot sink them to use sites);
// sched_barrier(0) stops MFMA hoisting past it (rule #18).  vmcnt(4) after the
// MFMA cluster keeps B(t+2) in flight across the tile boundary (T4).
// EPI: 0 none; 1 +biasv[col]; 3 +biasv[row];
//      4 exp(v*scale + bf2f(biasm[row*ldbm+col]))  (softmax numerator, bf16 out)
//      5 v * (1 / biasv[z*ldbm + row])             (late softmax rescale)
template <int EPI, typename OutT>
__global__ __launch_bounds__(512, 2) void gemm8p(
    const unsigned short* __restrict__ A, int lda, long long strA,
    const unsigned short* __restrict__ Bm, int ldb, long long strB,
    OutT* __restrict__ C, int ldc, long long strC, int K,
    const float* __restrict__ biasv,
    const unsigned short* __restrict__ biasm, int ldbm, float scale) {
  __shared__ __align__(16) char lds[131072];
  const int tid = threadIdx.x;
  const int wid = tid >> 6, lane = tid & 63;
  const int wm = wid >> 2, wn = wid & 3;
  const int l16 = lane & 15, lk = lane >> 4;
  const int zz = blockIdx.z;

  // XCD-aware block swizzle (all launches have gridDim.x*gridDim.y % 8 == 0)
  const int nx = gridDim.x;
  const int nwg = nx * gridDim.y;
  const int bid = blockIdx.y * nx + blockIdx.x;
  const int swz = (bid & 7) * (nwg >> 3) + (bid >> 3);
  const int tm = (swz % nx) * 256, tn = (swz / nx) * 256;

  A += (size_t)zz * strA;
  Bm += (size_t)zz * strB;
  C += (size_t)zz * strC;

  const int nt = K >> 6;  // K-tiles (callers guarantee nt >= 2, even)

  // swizzled chunk byte-offsets for ds_read (row&7 == l16&7 in all uses)
  const int q0 = ((lk ^ (l16 & 7)) << 4);
  const int q1 = (((lk | 4) ^ (l16 & 7)) << 4);
  // staging source decomposition (source chunk pre-swizzled, LDS dest linear)
  const int srow = lane >> 3;
  const int scol = ((lane & 7) ^ srow) << 3;  // element offset

  f32x4 acc[8][4];
#pragma unroll
  for (int i = 0; i < 8; ++i)
#pragma unroll
    for (int j = 0; j < 4; ++j) acc[i][j] = (f32x4){0.f, 0.f, 0.f, 0.f};

  short8 bF[4][2];

#define STAGE_A(tt, h)                                                              \
  {                                                                                 \
    const int buf_ = (tt) & 1, k0_ = (tt) << 6;                                     \
    { const unsigned short* g_ =                                                    \
          A + (size_t)(tm + (h) * 128 + wid * 16 + srow) * lda + k0_ + scol;        \
      async16(g_, lds + (buf_ * 2 + (h)) * 16384 + wid * 2048); }                   \
    { const unsigned short* g_ =                                                    \
          A + (size_t)(tm + (h) * 128 + wid * 16 + 8 + srow) * lda + k0_ + scol;    \
      async16(g_, lds + (buf_ * 2 + (h)) * 16384 + wid * 2048 + 1024); }            \
  }
#define STAGE_B(tt, h)                                                              \
  {                                                                                 \
    const int buf_ = (tt) & 1, k0_ = (tt) << 6;                                     \
    { const unsigned short* g_ =                                                    \
          Bm + (size_t)(tn + (h) * 128 + wid * 16 + srow) * ldb + k0_ + scol;       \
      async16(g_, lds + 65536 + (buf_ * 2 + (h)) * 16384 + wid * 2048); }           \
    { const unsigned short* g_ =                                                    \
          Bm + (size_t)(tn + (h) * 128 + wid * 16 + 8 + srow) * ldb + k0_ + scol;   \
      async16(g_, lds + 65536 + (buf_ * 2 + (h)) * 16384 + wid * 2048 + 1024); }    \
  }

  // PHASE(tt, cur_, p_): one of 4 phases of K-tile tt living in buffer cur_.
#define PHASE(tt, cur_, p_)                                                         \
  {                                                                                 \
    const char* aB = lds + ((cur_) * 2 + wm) * 16384 + l16 * 128;                   \
    const char* bB = lds + 65536 + ((cur_) * 2 + (wn >> 1)) * 16384 +               \
                     ((wn & 1) * 64 + l16) * 128;                                   \
    short8 a00 = *(const short8*)(aB + (2 * (p_)) * 2048 + q0);                     \
    short8 a01 = *(const short8*)(aB + (2 * (p_)) * 2048 + q1);                     \
    short8 a10 = *(const short8*)(aB + (2 * (p_) + 1) * 2048 + q0);                 \
    short8 a11 = *(const short8*)(aB + (2 * (p_) + 1) * 2048 + q1);                 \
    if ((p_) == 0) {                                                                \
      _Pragma("unroll")                                                             \
      for (int wc = 0; wc < 4; ++wc) {                                              \
        bF[wc][0] = *(const short8*)(bB + wc * 2048 + q0);                          \
        bF[wc][1] = *(const short8*)(bB + wc * 2048 + q1);                          \
      }                                                                             \
    }                                                                               \
    if ((p_) == 0 && (tt) + 1 < nt) STAGE_A((tt) + 1, 0);                           \
    if ((p_) == 1 && (tt) + 1 < nt) STAGE_A((tt) + 1, 1);                           \
    if ((p_) == 2 && (tt) + 2 < nt) STAGE_B((tt) + 2, 0);                           \
    if ((p_) == 3 && (tt) + 2 < nt) STAGE_B((tt) + 2, 1);                           \
    if ((p_) == 0) asm volatile("s_waitcnt lgkmcnt(8)");                            \
    __builtin_amdgcn_s_barrier();                                                   \
    asm volatile("s_waitcnt lgkmcnt(0)" ::: "memory");                              \
    __builtin_amdgcn_sched_barrier(0);                                              \
    __builtin_amdgcn_s_setprio(1);                                                  \
    _Pragma("unroll")                                                               \
    for (int wc = 0; wc < 4; ++wc) {                                                \
      acc[2 * (p_)][wc] =                                                           \
          __builtin_amdgcn_mfma_f32_16x16x32_bf16(a00, bF[wc][0], acc[2 * (p_)][wc], 0, 0, 0); \
      acc[2 * (p_)][wc] =                                                           \
          __builtin_amdgcn_mfma_f32_16x16x32_bf16(a01, bF[wc][1], acc[2 * (p_)][wc], 0, 0, 0); \
      acc[2 * (p_) + 1][wc] =                                                       \
          __builtin_amdgcn_mfma_f32_16x16x32_bf16(a10, bF[wc][0], acc[2 * (p_) + 1][wc], 0, 0, 0); \
      acc[2 * (p_) + 1][wc] =                                                       \
          __builtin_amdgcn_mfma_f32_16x16x32_bf16(a11, bF[wc][1], acc[2 * (p_) + 1][wc], 0, 0, 0); \
    }                                                                               \
    __builtin_amdgcn_s_setprio(0);                                                  \
    if ((p_) == 3) {                                                                \
      if ((tt) + 2 < nt) asm volatile("s_waitcnt vmcnt(4)" ::: "memory");           \
      else               asm volatile("s_waitcnt vmcnt(0)" ::: "memory");           \
    }                                                                               \
    __builtin_amdgcn_s_barrier();                                                   \
  }

  // prologue: tile0 all 4 halves + tile1 B halves (B consumed 2 tiles ahead)
  STAGE_A(0, 0); STAGE_A(0, 1); STAGE_B(0, 0); STAGE_B(0, 1);
  STAGE_B(1, 0); STAGE_B(1, 1);
  asm volatile("s_waitcnt vmcnt(4)" ::: "memory");  // tile0 landed; tile1.B in flight
  __builtin_amdgcn_s_barrier();

  int t = 0;
  for (; t + 1 < nt; t += 2) {
    PHASE(t, 0, 0) PHASE(t, 0, 1) PHASE(t, 0, 2) PHASE(t, 0, 3)
    PHASE(t + 1, 1, 0) PHASE(t + 1, 1, 1) PHASE(t + 1, 1, 2) PHASE(t + 1, 1, 3)
  }
  if (t < nt) {  // odd-nt tail (not hit for K=1024/2048)
    const int c = t & 1;
    if (c == 0) { PHASE(t, 0, 0) PHASE(t, 0, 1) PHASE(t, 0, 2) PHASE(t, 0, 3) }
    else        { PHASE(t, 1, 0) PHASE(t, 1, 1) PHASE(t, 1, 2) PHASE(t, 1, 3) }
  }
#undef STAGE_A
#undef STAGE_B
#undef PHASE

  // epilogue: D row=(lane>>4)*4+r, col=lane&15 per 16x16 frag (verified mapping)
#pragma unroll
  for (int fr = 0; fr < 8; ++fr) {
    const int rbase = tm + wm * 128 + fr * 16 + lk * 4;
    float rin[4];
    if (EPI == 5) {
#pragma unroll
      for (int r = 0; r < 4; ++r)
        rin[r] = 1.0f / biasv[(size_t)zz * ldbm + rbase + r];
    }
#pragma unroll
    for (int wc = 0; wc < 4; ++wc) {
      const int col = tn + wn * 64 + wc * 16 + l16;
#pragma unroll
      for (int r = 0; r < 4; ++r) {
        float v = acc[fr][wc][r];
        const int row = rbase + r;
        if (EPI == 1) v += biasv[col];
        if (EPI == 3) v += biasv[row];
        if (EPI == 4) v = __expf(v * scale + bf2f(biasm[(size_t)row * ldbm + col]));
        if (EPI == 5) v *= rin[r];
        storeC(&C[(size_t)row * ldc + col], v);
      }
    }
  }
}

// ---------------- row sums of expS (bf16): R[row] = sum_s P[row,s] ----------------
__global__ __launch_bounds__(256) void rowsum(const unsigned short* __restrict__ P,
                                              float* __restrict__ R) {
  const size_t row = (size_t)blockIdx.y * T_DIM + blockIdx.x;
  const int tid = threadIdx.x;
  const int wid = tid >> 6;
  __shared__ float red[4];

  short8 v = ((const short8*)(P + row * T_DIM))[tid];
  float s = 0.f;
#pragma unroll
  for (int j = 0; j < 8; ++j) s += bf2f((unsigned short)v[j]);
#pragma unroll
  for (int o = 1; o < 64; o <<= 1) s += __shfl_xor(s, o);
  if ((tid & 63) == 0) red[wid] = s;
  __syncthreads();
  if (tid == 0) R[row] = (red[0] + red[1]) + (red[2] + red[3]);
}

// ---------------- launch ----------------
extern "C" void kernel_launch(void* const* d_in, const int* in_sizes, int n_in,
                              void* d_out, int out_size, void* d_ws, size_t ws_size,
                              hipStream_t stream) {
  const float* x = (const float*)d_in[0];     // [8,2048,1024]
  const float* bias = (const float*)d_in[1];  // [2048,2048] fp32
  const float* Wqkv = (const float*)d_in[2];  // [3072,1024]
  const float* bqkv = (const float*)d_in[3];  // [3072]
  const float* Wout = (const float*)d_in[4];  // [1024,1024]
  const float* bout = (const float*)d_in[5];  // [1024]
  float* out = (float*)d_out;                 // [8,2048,1024] fp32

  char* ws = (char*)d_ws;
  unsigned short* Xb    = (unsigned short*)(ws + 0);          // 33.5MB; reused as Valb
  unsigned short* Wqkvb = (unsigned short*)(ws + 33554432);   // 6.3MB [3072,1024]
  unsigned short* Woutb = (unsigned short*)(ws + 39845888);   // 2.1MB
  unsigned short* QKb   = (unsigned short*)(ws + 41943040);   // 67MB [b,t,2048] (Q|K)
  unsigned short* VTb   = (unsigned short*)(ws + 109051904);  // 33.5MB [1024, 8*2048]
  unsigned short* biasb = (unsigned short*)(ws + 142606336);  // 8.4MB [2048,2048] bf16
  unsigned short* P     = (unsigned short*)(ws + 150994944);  // 67MB [b,2048,2048] expS bf16
  unsigned short* Valb  = Xb;                                 // overlays Xb (dead after V-GEMM)
  // row sums live in the tail of d_out (scratch until outproj overwrites it)
  float*          R     = out + ((size_t)out_size - B_DIM * T_DIM);

  const long long sQK  = (long long)T_DIM * 2048;   // elements
  const long long sTT  = (long long)T_DIM * T_DIM;  // P batch stride (elements)
  const long long sTE  = (long long)T_DIM * E_DIM;

  // 1) fp32 -> bf16 conversions
  cvt_bf16<<<16384, 256, 0, stream>>>((const float4*)x, (ushort4*)Xb);
  cvt_bf16<<<3072, 256, 0, stream>>>((const float4*)Wqkv, (ushort4*)Wqkvb);
  cvt_bf16<<<1024, 256, 0, stream>>>((const float4*)Wout, (ushort4*)Woutb);
  cvt_bf16<<<4096, 256, 0, stream>>>((const float4*)bias, (ushort4*)biasb);

  // 2) QK projection: [16384,2048] = Xb[16384,1024]*Wqk^T + bqk
  gemm8p<1, unsigned short><<<dim3(64, 8, 1), 512, 0, stream>>>(
      Xb, 1024, 0, Wqkvb, 1024, 0, QKb, 2048, 0, 1024, bqkv, nullptr, 0, 0.f);

  // 3) V projection, TRANSPOSED output: VT[d, b*T+t] = Wv[d,:].x[b,t,:] + bv[d]
  gemm8p<3, unsigned short><<<dim3(4, 64, 1), 512, 0, stream>>>(
      Wqkvb + (size_t)2048 * 1024, 1024, 0, Xb, 1024, 0,
      VTb, 16384, 0, 1024, bqkv + 2048, nullptr, 0, 0.f);

  // 4) logits + fused exp (no max-sub; logits bounded ~|2|):
  //    P[z,t,s] = exp((Q_t.K_s)/32 + bias[t,s])  (bf16)
  gemm8p<4, unsigned short><<<dim3(8, 8, B_DIM), 512, 0, stream>>>(
      QKb, 2048, sQK, QKb + 1024, 2048, sQK, P, T_DIM, sTT, 1024,
      nullptr, biasb, T_DIM, 0.03125f);

  // 5) deterministic row sums of expS
  rowsum<<<dim3(T_DIM, B_DIM), 256, 0, stream>>>(P, R);

  // 6) PV with late rescale: Val[z,t,d] = (sum_s P[z,t,s]*VT[d,z*T+s]) / R[z,t]
  gemm8p<5, unsigned short><<<dim3(8, 4, B_DIM), 512, 0, stream>>>(
      P, T_DIM, sTT, VTb, 8 * T_DIM, T_DIM,
      Valb, E_DIM, sTE, T_DIM, R, nullptr, T_DIM, 0.f);

  // 7) output projection: out = Val[16384,1024]*Wout^T + bout
  gemm8p<1, float><<<dim3(64, 4, 1), 512, 0, stream>>>(
      Valb, 1024, 0, Woutb, 1024, 0, out, 1024, 0, 1024, bout, nullptr, 0, 0.f);
}

// Round 7
// 320.450 us; speedup vs baseline: 1.0773x; 1.0773x over previous
//
#include <hip/hip_runtime.h>
#include <hip/hip_bf16.h>

// Problem: B=8, T=2048, D_IN=D_EMB=D_OUT=1024
#define B_DIM 8
#define T_DIM 2048
#define E_DIM 1024

typedef __attribute__((ext_vector_type(8))) short short8;
typedef __attribute__((ext_vector_type(4))) float f32x4;

__device__ __forceinline__ unsigned short f2bf(float f) {
  union { float f; unsigned u; } v; v.f = f;
  unsigned r = v.u + 0x7fffu + ((v.u >> 16) & 1u);
  return (unsigned short)(r >> 16);
}
__device__ __forceinline__ float bf2f(unsigned short u) {
  union { unsigned u; float f; } v; v.u = ((unsigned)u) << 16;
  return v.f;
}

__device__ __forceinline__ void async16(const void* g, void* l) {
  __builtin_amdgcn_global_load_lds(
      (const __attribute__((address_space(1))) unsigned int*)g,
      (__attribute__((address_space(3))) unsigned int*)l, 16, 0, 0);
}

__device__ __forceinline__ void storeC(float* p, float v) { *p = v; }
__device__ __forceinline__ void storeC(unsigned short* p, float v) { *p = f2bf(v); }

// ---------------- fp32 -> bf16 conversion (vectorized) ----------------
__global__ __launch_bounds__(256) void cvt_bf16(const float4* __restrict__ in,
                                                ushort4* __restrict__ out) {
  size_t i = (size_t)blockIdx.x * 256 + threadIdx.x;
  float4 v = in[i];
  ushort4 o;
  o.x = f2bf(v.x); o.y = f2bf(v.y); o.z = f2bf(v.z); o.w = f2bf(v.w);
  out[i] = o;
}

// ------- x cvt producing BOTH row-major Xb [16384,1024] and transposed XT [1024,16384] ----
__global__ __launch_bounds__(256) void cvt_x_dual(const float* __restrict__ x,
                                                  unsigned short* __restrict__ Xb,
                                                  unsigned short* __restrict__ XT) {
  __shared__ unsigned short tl[64][65];
  const int t0 = blockIdx.x * 64, i0 = blockIdx.y * 64;
  const int tx = threadIdx.x & 63, ty = threadIdx.x >> 6;
#pragma unroll
  for (int it = 0; it < 16; ++it) {
    int r = it * 4 + ty;
    unsigned short u = f2bf(x[(size_t)(t0 + r) * 1024 + i0 + tx]);
    Xb[(size_t)(t0 + r) * 1024 + i0 + tx] = u;
    tl[r][tx] = u;
  }
  __syncthreads();
#pragma unroll
  for (int it = 0; it < 16; ++it) {
    int r = it * 4 + ty;
    XT[(size_t)(i0 + r) * 16384 + t0 + tx] = tl[tx][r];
  }
}

// ------- transpose-cvt 1024x1024: outT[c,r] = bf16(in[r,c]) ----------------
__global__ __launch_bounds__(256) void cvt_t64(const float* __restrict__ in,
                                               unsigned short* __restrict__ outT) {
  __shared__ unsigned short tl[64][65];
  const int r0 = blockIdx.x * 64, c0 = blockIdx.y * 64;
  const int tx = threadIdx.x & 63, ty = threadIdx.x >> 6;
#pragma unroll
  for (int it = 0; it < 16; ++it) {
    int r = it * 4 + ty;
    tl[r][tx] = f2bf(in[(size_t)(r0 + r) * 1024 + c0 + tx]);
  }
  __syncthreads();
#pragma unroll
  for (int it = 0; it < 16; ++it) {
    int r = it * 4 + ty;
    outT[(size_t)(c0 + r) * 1024 + r0 + tx] = tl[tx][r];
  }
}

// ------- bfused[o] = sum_v Wout[o,v]*bv[v] + bout[o]  (one wave per o) -------------
__global__ __launch_bounds__(256) void bfused_k(const unsigned short* __restrict__ Woutb,
                                                const float* __restrict__ bqkv,
                                                const float* __restrict__ bout,
                                                float* __restrict__ bf) {
  const int o = blockIdx.x * 4 + (threadIdx.x >> 6);
  const int lane = threadIdx.x & 63;
  const short8 w0 = *(const short8*)&Woutb[(size_t)o * 1024 + lane * 16];
  const short8 w1 = *(const short8*)&Woutb[(size_t)o * 1024 + lane * 16 + 8];
  const float* bv = bqkv + 2048 + lane * 16;
  float s = 0.f;
#pragma unroll
  for (int j = 0; j < 8; ++j) s += bf2f((unsigned short)w0[j]) * bv[j];
#pragma unroll
  for (int j = 0; j < 8; ++j) s += bf2f((unsigned short)w1[j]) * bv[8 + j];
#pragma unroll
  for (int off = 1; off < 64; off <<= 1) s += __shfl_xor(s, off);
  if (lane == 0) bf[o] = s + bout[o];
}

// ------- finish rowsums: R[z,row] = sum over 32 slabs of psum[z][slab][row] -------
__global__ __launch_bounds__(256) void finish_rowsum(const float* __restrict__ psum,
                                                     float* __restrict__ R) {
  const int z = blockIdx.y;
  const int row = blockIdx.x * 256 + threadIdx.x;
  const float* p = psum + (size_t)z * 32 * 2048 + row;
  float s = 0.f;
#pragma unroll
  for (int k = 0; k < 32; ++k) s += p[k * 2048];
  R[(size_t)z * 2048 + row] = s;
}

// ============ 128x128 bf16 GEMM (R2-validated core) for tiny Wf = Wout*Wv^T ==========
__global__ __launch_bounds__(256) void gemm128(
    const unsigned short* __restrict__ A, int lda,
    const unsigned short* __restrict__ Bmat, int ldb,
    unsigned short* __restrict__ C, int ldc, int K) {
  __shared__ __align__(16) unsigned short Al[128 * 32];
  __shared__ __align__(16) unsigned short Bl[128 * 32];
  const int tid = threadIdx.x;
  const int wid = tid >> 6, lane = tid & 63;
  const int wm = wid >> 1, wn = wid & 1;
  const int nx = gridDim.x, nwg = nx * gridDim.y;
  const int bid = blockIdx.y * nx + blockIdx.x;
  const int swz = (bid & 7) * (nwg >> 3) + (bid >> 3);
  const int tm = (swz % nx) * 128, tn = (swz / nx) * 128;
  const int l16 = lane & 15, lk = lane >> 4;

  f32x4 acc[4][4];
#pragma unroll
  for (int i = 0; i < 4; ++i)
#pragma unroll
    for (int j = 0; j < 4; ++j) acc[i][j] = (f32x4){0.f, 0.f, 0.f, 0.f};

  const int ks = (lk ^ ((l16 >> 1) & 3)) * 8;

  for (int k0 = 0; k0 < K; k0 += 32) {
    __syncthreads();
#pragma unroll
    for (int it = 0; it < 2; ++it) {
      int chunk = it * 256 + tid;
      int row = chunk >> 2;
      int q = chunk & 3;
      int qs = q ^ ((row >> 1) & 3);
      const char* g = (const char*)(A + (size_t)(tm + row) * lda + k0) + qs * 16;
      async16(g, ((char*)Al) + it * 4096 + wid * 1024);
    }
#pragma unroll
    for (int it = 0; it < 2; ++it) {
      int chunk = it * 256 + tid;
      int row = chunk >> 2;
      int q = chunk & 3;
      int qs = q ^ ((row >> 1) & 3);
      const char* g = (const char*)(Bmat + (size_t)(tn + row) * ldb + k0) + qs * 16;
      async16(g, ((char*)Bl) + it * 4096 + wid * 1024);
    }
    __syncthreads();

    short8 a[4], b[4];
#pragma unroll
    for (int i = 0; i < 4; ++i)
      a[i] = *(const short8*)&Al[(wm * 64 + i * 16 + l16) * 32 + ks];
#pragma unroll
    for (int j = 0; j < 4; ++j)
      b[j] = *(const short8*)&Bl[(wn * 64 + j * 16 + l16) * 32 + ks];
#pragma unroll
    for (int i = 0; i < 4; ++i)
#pragma unroll
      for (int j = 0; j < 4; ++j)
        acc[i][j] = __builtin_amdgcn_mfma_f32_16x16x32_bf16(a[i], b[j], acc[i][j], 0, 0, 0);
  }

#pragma unroll
  for (int i = 0; i < 4; ++i)
#pragma unroll
    for (int j = 0; j < 4; ++j) {
      int col = tn + wn * 64 + j * 16 + l16;
      int rbase = tm + wm * 64 + i * 16 + lk * 4;
#pragma unroll
      for (int r = 0; r < 4; ++r)
        C[(size_t)(rbase + r) * ldc + col] = f2bf(acc[i][j][r]);
    }
}

// ============ 256x256 8-phase bf16 GEMM: C[M,N] = A[M,K]*B[N,K]^T (+epilogue) ========
// (R6 core, frozen.)  512 threads = 8 waves (2M x 4N), BK=64, 128KB LDS, chunk swizzle
// q' = q ^ (row&7) both-sides (rule #21); m201 phase discipline; counted vmcnt(4) (T4).
// EPI: 0 none; 1 +biasv[col];
//      4 exp(v*scale + bf2f(biasm[row*ldbm+col])), bf16 out, + per-block row partial
//        sums -> psum[(z*8+tn_blk)*4+wn][row]   (deterministic: unique writers)
//      5 v * (1 / biasv[z*ldbm + row])          (late softmax rescale)
template <int EPI, typename OutT>
__global__ __launch_bounds__(512, 2) void gemm8p(
    const unsigned short* __restrict__ A, int lda, long long strA,
    const unsigned short* __restrict__ Bm, int ldb, long long strB,
    OutT* __restrict__ C, int ldc, long long strC, int K,
    const float* __restrict__ biasv,
    const unsigned short* __restrict__ biasm, int ldbm, float scale,
    float* __restrict__ psum) {
  __shared__ __align__(16) char lds[131072];
  const int tid = threadIdx.x;
  const int wid = tid >> 6, lane = tid & 63;
  const int wm = wid >> 2, wn = wid & 3;
  const int l16 = lane & 15, lk = lane >> 4;
  const int zz = blockIdx.z;

  const int nx = gridDim.x;
  const int nwg = nx * gridDim.y;
  const int bid = blockIdx.y * nx + blockIdx.x;
  const int swz = (bid & 7) * (nwg >> 3) + (bid >> 3);
  const int tm = (swz % nx) * 256, tn = (swz / nx) * 256;

  A += (size_t)zz * strA;
  Bm += (size_t)zz * strB;
  C += (size_t)zz * strC;

  const int nt = K >> 6;  // callers guarantee nt >= 2, even

  const int q0 = ((lk ^ (l16 & 7)) << 4);
  const int q1 = (((lk | 4) ^ (l16 & 7)) << 4);
  const int srow = lane >> 3;
  const int scol = ((lane & 7) ^ srow) << 3;

  f32x4 acc[8][4];
#pragma unroll
  for (int i = 0; i < 8; ++i)
#pragma unroll
    for (int j = 0; j < 4; ++j) acc[i][j] = (f32x4){0.f, 0.f, 0.f, 0.f};

  short8 bF[4][2];

#define STAGE_A(tt, h)                                                              \
  {                                                                                 \
    const int buf_ = (tt) & 1, k0_ = (tt) << 6;                                     \
    { const unsigned short* g_ =                                                    \
          A + (size_t)(tm + (h) * 128 + wid * 16 + srow) * lda + k0_ + scol;        \
      async16(g_, lds + (buf_ * 2 + (h)) * 16384 + wid * 2048); }                   \
    { const unsigned short* g_ =                                                    \
          A + (size_t)(tm + (h) * 128 + wid * 16 + 8 + srow) * lda + k0_ + scol;    \
      async16(g_, lds + (buf_ * 2 + (h)) * 16384 + wid * 2048 + 1024); }            \
  }
#define STAGE_B(tt, h)                                                              \
  {                                                                                 \
    const int buf_ = (tt) & 1, k0_ = (tt) << 6;                                     \
    { const unsigned short* g_ =                                                    \
          Bm + (size_t)(tn + (h) * 128 + wid * 16 + srow) * ldb + k0_ + scol;       \
      async16(g_, lds + 65536 + (buf_ * 2 + (h)) * 16384 + wid * 2048); }           \
    { const unsigned short* g_ =                                                    \
          Bm + (size_t)(tn + (h) * 128 + wid * 16 + 8 + srow) * ldb + k0_ + scol;   \
      async16(g_, lds + 65536 + (buf_ * 2 + (h)) * 16384 + wid * 2048 + 1024); }    \
  }
#define PHASE(tt, cur_, p_)                                                         \
  {                                                                                 \
    const char* aB = lds + ((cur_) * 2 + wm) * 16384 + l16 * 128;                   \
    const char* bB = lds + 65536 + ((cur_) * 2 + (wn >> 1)) * 16384 +               \
                     ((wn & 1) * 64 + l16) * 128;                                   \
    short8 a00 = *(const short8*)(aB + (2 * (p_)) * 2048 + q0);                     \
    short8 a01 = *(const short8*)(aB + (2 * (p_)) * 2048 + q1);                     \
    short8 a10 = *(const short8*)(aB + (2 * (p_) + 1) * 2048 + q0);                 \
    short8 a11 = *(const short8*)(aB + (2 * (p_) + 1) * 2048 + q1);                 \
    if ((p_) == 0) {                                                                \
      _Pragma("unroll")                                                             \
      for (int wc = 0; wc < 4; ++wc) {                                              \
        bF[wc][0] = *(const short8*)(bB + wc * 2048 + q0);                          \
        bF[wc][1] = *(const short8*)(bB + wc * 2048 + q1);                          \
      }                                                                             \
    }                                                                               \
    if ((p_) == 0 && (tt) + 1 < nt) STAGE_A((tt) + 1, 0);                           \
    if ((p_) == 1 && (tt) + 1 < nt) STAGE_A((tt) + 1, 1);                           \
    if ((p_) == 2 && (tt) + 2 < nt) STAGE_B((tt) + 2, 0);                           \
    if ((p_) == 3 && (tt) + 2 < nt) STAGE_B((tt) + 2, 1);                           \
    if ((p_) == 0) asm volatile("s_waitcnt lgkmcnt(8)");                            \
    __builtin_amdgcn_s_barrier();                                                   \
    asm volatile("s_waitcnt lgkmcnt(0)" ::: "memory");                              \
    __builtin_amdgcn_sched_barrier(0);                                              \
    __builtin_amdgcn_s_setprio(1);                                                  \
    _Pragma("unroll")                                                               \
    for (int wc = 0; wc < 4; ++wc) {                                                \
      acc[2 * (p_)][wc] =                                                           \
          __builtin_amdgcn_mfma_f32_16x16x32_bf16(a00, bF[wc][0], acc[2 * (p_)][wc], 0, 0, 0); \
      acc[2 * (p_)][wc] =                                                           \
          __builtin_amdgcn_mfma_f32_16x16x32_bf16(a01, bF[wc][1], acc[2 * (p_)][wc], 0, 0, 0); \
      acc[2 * (p_) + 1][wc] =                                                       \
          __builtin_amdgcn_mfma_f32_16x16x32_bf16(a10, bF[wc][0], acc[2 * (p_) + 1][wc], 0, 0, 0); \
      acc[2 * (p_) + 1][wc] =                                                       \
          __builtin_amdgcn_mfma_f32_16x16x32_bf16(a11, bF[wc][1], acc[2 * (p_) + 1][wc], 0, 0, 0); \
    }                                                                               \
    __builtin_amdgcn_s_setprio(0);                                                  \
    if ((p_) == 3) {                                                                \
      if ((tt) + 2 < nt) asm volatile("s_waitcnt vmcnt(4)" ::: "memory");           \
      else               asm volatile("s_waitcnt vmcnt(0)" ::: "memory");           \
    }                                                                               \
    __builtin_amdgcn_s_barrier();                                                   \
  }

  STAGE_A(0, 0); STAGE_A(0, 1); STAGE_B(0, 0); STAGE_B(0, 1);
  STAGE_B(1, 0); STAGE_B(1, 1);
  asm volatile("s_waitcnt vmcnt(4)" ::: "memory");
  __builtin_amdgcn_s_barrier();

  int t = 0;
  for (; t + 1 < nt; t += 2) {
    PHASE(t, 0, 0) PHASE(t, 0, 1) PHASE(t, 0, 2) PHASE(t, 0, 3)
    PHASE(t + 1, 1, 0) PHASE(t + 1, 1, 1) PHASE(t + 1, 1, 2) PHASE(t + 1, 1, 3)
  }
  if (t < nt) {
    const int c = t & 1;
    if (c == 0) { PHASE(t, 0, 0) PHASE(t, 0, 1) PHASE(t, 0, 2) PHASE(t, 0, 3) }
    else        { PHASE(t, 1, 0) PHASE(t, 1, 1) PHASE(t, 1, 2) PHASE(t, 1, 3) }
  }
#undef STAGE_A
#undef STAGE_B
#undef PHASE

  // epilogue: D row=(lane>>4)*4+r, col=lane&15 per 16x16 frag (verified mapping)
#pragma unroll
  for (int fr = 0; fr < 8; ++fr) {
    const int rbase = tm + wm * 128 + fr * 16 + lk * 4;
    float rin[4];
    if (EPI == 5) {
#pragma unroll
      for (int r = 0; r < 4; ++r)
        rin[r] = 1.0f / biasv[(size_t)zz * ldbm + rbase + r];
    }
    float rs[4] = {0.f, 0.f, 0.f, 0.f};
#pragma unroll
    for (int wc = 0; wc < 4; ++wc) {
      const int col = tn + wn * 64 + wc * 16 + l16;
#pragma unroll
      for (int r = 0; r < 4; ++r) {
        float v = acc[fr][wc][r];
        const int row = rbase + r;
        if (EPI == 1) v += biasv[col];
        if (EPI == 4) {
          v = __expf(v * scale + bf2f(biasm[(size_t)row * ldbm + col]));
          rs[r] += v;
        }
        if (EPI == 5) v *= rin[r];
        storeC(&C[(size_t)row * ldc + col], v);
      }
    }
    if (EPI == 4) {
#pragma unroll
      for (int r = 0; r < 4; ++r) {
#pragma unroll
        for (int off = 1; off < 16; off <<= 1) rs[r] += __shfl_xor(rs[r], off);
      }
      if (l16 == 0) {
        const int slab = ((zz * 8 + (tn >> 8)) * 4 + wn);
#pragma unroll
        for (int r = 0; r < 4; ++r)
          psum[(size_t)slab * 2048 + rbase + r] = rs[r];
      }
    }
  }
}

// ---------------- launch ----------------
extern "C" void kernel_launch(void* const* d_in, const int* in_sizes, int n_in,
                              void* d_out, int out_size, void* d_ws, size_t ws_size,
                              hipStream_t stream) {
  const float* x = (const float*)d_in[0];     // [8,2048,1024]
  const float* bias = (const float*)d_in[1];  // [2048,2048] fp32
  const float* Wqkv = (const float*)d_in[2];  // [3072,1024]
  const float* bqkv = (const float*)d_in[3];  // [3072]
  const float* Wout = (const float*)d_in[4];  // [1024,1024]
  const float* bout = (const float*)d_in[5];  // [1024]
  float* out = (float*)d_out;                 // [8,2048,1024] fp32

  char* ws = (char*)d_ws;
  unsigned short* Xb    = (unsigned short*)(ws + 0);          // 33.5MB; reused as Valb
  unsigned short* XTb   = (unsigned short*)(ws + 33554432);   // 33.5MB [1024, 16384]
  unsigned short* WqkB  = (unsigned short*)(ws + 67108864);   // 4.2MB [2048,1024]
  unsigned short* WvTb  = (unsigned short*)(ws + 71303168);   // 2.1MB [i,v]
  unsigned short* Woutb = (unsigned short*)(ws + 73400320);   // 2.1MB [o,v]
  unsigned short* Wfb   = (unsigned short*)(ws + 75497472);   // 2.1MB [o,i]
  float*          bfv   = (float*)(ws + 77594624);            // 4KB
  unsigned short* QKb   = (unsigned short*)(ws + 77598720);   // 67MB [b,t,2048]
  unsigned short* biasb = (unsigned short*)(ws + 144707584);  // 8.4MB bf16
  unsigned short* P     = (unsigned short*)(ws + 153096192);  // 67MB [b,2048,2048] expS
  float*          psum  = (float*)(ws + 220205056);           // 2MB [8][32][2048]
  unsigned short* Valb  = Xb;                                 // overlays Xb (dead after QK)
  float*          R     = out + ((size_t)out_size - B_DIM * T_DIM);  // out tail scratch

  const long long sQK = (long long)T_DIM * 2048;
  const long long sTT = (long long)T_DIM * T_DIM;
  const long long sTE = (long long)T_DIM * E_DIM;

  // 1) conversions: x -> Xb + XT (fused transpose); Wq|Wk; Wv^T; Wout; bias
  cvt_x_dual<<<dim3(256, 16), 256, 0, stream>>>(x, Xb, XTb);
  cvt_bf16<<<2048, 256, 0, stream>>>((const float4*)Wqkv, (ushort4*)WqkB);
  cvt_t64<<<dim3(16, 16), 256, 0, stream>>>(Wqkv + (size_t)2048 * 1024, WvTb);
  cvt_bf16<<<1024, 256, 0, stream>>>((const float4*)Wout, (ushort4*)Woutb);
  cvt_bf16<<<4096, 256, 0, stream>>>((const float4*)bias, (ushort4*)biasb);

  // 2) fused epilogue constants: bfv = Wout*bv + bout;  Wf = Wout*Wv  ([o,i])
  bfused_k<<<256, 256, 0, stream>>>(Woutb, bqkv, bout, bfv);
  gemm128<<<dim3(8, 8), 256, 0, stream>>>(Woutb, 1024, WvTb, 1024, Wfb, 1024, 1024);

  // 3) QK projection: [16384,2048] = Xb*Wqk^T + bqk
  gemm8p<1, unsigned short><<<dim3(64, 8, 1), 512, 0, stream>>>(
      Xb, 1024, 0, WqkB, 1024, 0, QKb, 2048, 0, 1024, bqkv, nullptr, 0, 0.f, nullptr);

  // 4) logits + fused exp + partial rowsums: P[z,t,s] = exp((Q_t.K_s)/32 + bias[t,s])
  gemm8p<4, unsigned short><<<dim3(8, 8, B_DIM), 512, 0, stream>>>(
      QKb, 2048, sQK, QKb + 1024, 2048, sQK, P, T_DIM, sTT, 1024,
      nullptr, biasb, T_DIM, 0.03125f, psum);

  // 5) finish rowsums -> R[z,t]
  finish_rowsum<<<dim3(8, B_DIM), 256, 0, stream>>>(psum, R);

  // 6) PX with late rescale: Val[z,t,i] = (sum_s P[z,t,s]*X[z,s,i]) / R[z,t]
  gemm8p<5, unsigned short><<<dim3(8, 4, B_DIM), 512, 0, stream>>>(
      P, T_DIM, sTT, XTb, 8 * T_DIM, T_DIM,
      Valb, E_DIM, sTE, T_DIM, R, nullptr, T_DIM, 0.f, nullptr);

  // 7) fused output projection: out = Val*Wf^T + bfv   (absorbs Wv, Wout, bv, bout)
  gemm8p<1, float><<<dim3(64, 4, 1), 512, 0, stream>>>(
      Valb, 1024, 0, Wfb, 1024, 0, out, 1024, 0, 1024, bfv, nullptr, 0, 0.f, nullptr);
}